// Round 10
// baseline (2468.537 us; speedup 1.0000x reference)
//
#include <hip/hip_runtime.h>
#include <hip/hip_bf16.h>

#define VOCAB 50000
#define EDIM 256
#define HDIM 256
#define BATCH 64
#define SEQ 2048

typedef __attribute__((ext_vector_type(2))) float v2f;

// ---------------- kernel 0: transpose W_ih (H x E) -> W_T (E x H) -------------
__global__ void k_transpose(const float* __restrict__ W, float* __restrict__ WT) {
    int idx = blockIdx.x * 256 + threadIdx.x;
    int e = idx >> 8;
    int i = idx & 255;
    WT[idx] = W[i * 256 + e];
}

// ---------------- kernel 1: P[v][i] = sum_e emb[v][e] * W_ih[i][e] ------------
__global__ __launch_bounds__(256) void k_project(const float* __restrict__ emb,
                                                 const float* __restrict__ WT,
                                                 float* __restrict__ P) {
    __shared__ float etile[32 * 256];
    const int v0 = blockIdx.x * 32;
    const int tid = threadIdx.x;

    #pragma unroll 4
    for (int k = 0; k < 32; ++k) {
        int v = v0 + k;
        etile[k * 256 + tid] = (v < VOCAB) ? emb[(size_t)v * 256 + tid] : 0.0f;
    }
    __syncthreads();

    float acc[32];
    #pragma unroll
    for (int k = 0; k < 32; ++k) acc[k] = 0.0f;

    for (int e0 = 0; e0 < 256; e0 += 4) {
        float w0 = WT[(size_t)(e0 + 0) * 256 + tid];
        float w1 = WT[(size_t)(e0 + 1) * 256 + tid];
        float w2 = WT[(size_t)(e0 + 2) * 256 + tid];
        float w3 = WT[(size_t)(e0 + 3) * 256 + tid];
        #pragma unroll
        for (int k = 0; k < 32; ++k) {
            float4 ev = *(const float4*)&etile[k * 256 + e0];
            acc[k] = fmaf(ev.x, w0, acc[k]);
            acc[k] = fmaf(ev.y, w1, acc[k]);
            acc[k] = fmaf(ev.z, w2, acc[k]);
            acc[k] = fmaf(ev.w, w3, acc[k]);
        }
    }
    #pragma unroll 4
    for (int k = 0; k < 32; ++k) {
        int v = v0 + k;
        if (v < VOCAB) P[(size_t)v * 256 + tid] = acc[k];
    }
}

// ---------------- kernel 2: recurrence -----------------------------------------
// ROW-PAIR split (R9 lesson: in-wave COLUMN reduce forces multi-address LDS
// reads, +400 cyc/step; R4 lesson: wave-uniform broadcast reads are ~free).
// 512 threads = 8 waves. Wave w owns rows 32w..32w+31. Lane l: row = 32w+(l>>1),
// half = l&1 -> cols half*128..+127. 128 weights/thread as 64 v2f (pk-FMA).
// h-read: float4 stream, only TWO distinct addresses per instr across the wave
// (even/odd lanes differ by 512B = same bank, 2-way = free). Reduce = ONE
// quad_perm DPP add (lane pair 2r<->2r+1, pure VALU). Even lane finalizes
// (xp + tanh) and writes h[row] (stride-1 b32, banks 0..31). Double-buffered h,
// ONE barrier per step. No partials array, no LDS roundtrip.
__device__ __forceinline__ float tanh_fast(float x) {
    float ax = fabsf(x);
    float e  = __expf(-2.0f * ax);
    float r  = (1.0f - e) / (1.0f + e);
    return copysignf(r, x);
}

// quad_perm [1,0,3,2]: swap lanes within each pair (ctrl = 2<<6 | 3<<4 | 0<<2 | 1)
__device__ __forceinline__ float pair_swap_add(float a) {
    int t = __builtin_amdgcn_update_dpp(0, __float_as_int(a), 0xB1, 0xf, 0xf, true);
    return a + __int_as_float(t);
}

__global__ __launch_bounds__(512, 2) void k_rnn(const int* __restrict__ tokens,
                                                const int* __restrict__ lengths,
                                                const float* __restrict__ P,
                                                const float* __restrict__ Whh,
                                                const float* __restrict__ Wcls,
                                                const float* __restrict__ bcls,
                                                float* __restrict__ out) {
    __shared__ float hbuf[2][256];
    __shared__ int   tok_lds[SEQ];

    const int b   = blockIdx.x;
    const int tid = threadIdx.x;
    const int len = lengths[b];

    #pragma unroll
    for (int k = 0; k < 4; ++k)
        tok_lds[tid + k * 512] = tokens[b * SEQ + tid + k * 512];
    if (tid < 256) hbuf[0][tid] = 0.0f;

    const int w    = tid >> 6;           // wave id 0..7 (row block)
    const int l    = tid & 63;           // lane
    const int half = l & 1;              // column half (0: j<128, 1: j>=128)
    const int row  = 32 * w + (l >> 1);  // this lane's row

    // ---- weights: W[row][half*128 .. +127] -> 64 packed v2f regs ----
    v2f wp[64];
    {
        const float4* Wr = (const float4*)(Whh + (size_t)row * 256 + half * 128);
        #pragma unroll
        for (int m = 0; m < 32; ++m) {
            float4 q = Wr[m];
            wp[2 * m]     = (v2f){q.x, q.y};
            wp[2 * m + 1] = (v2f){q.z, q.w};
        }
    }
    __syncthreads();

    const bool fin = (half == 0);
    float xp_cur = 0.0f, xp_next = 0.0f;
    if (fin) xp_cur = P[(size_t)tok_lds[0] * 256 + row];

    for (int t = 0; t < len; ++t) {
        if (fin && t + 1 < len)
            xp_next = P[(size_t)tok_lds[t + 1] * 256 + row];   // in flight across FMA phase

        // ---- FMA: 32 near-uniform b128 reads, 64 pk-FMA, 4 indep chains ----
        const float4* hv = (const float4*)&hbuf[t & 1][half * 128];
        v2f a0 = (v2f){0.f, 0.f}, a1 = a0, a2 = a0, a3 = a0;
        #pragma unroll
        for (int m = 0; m < 32; m += 2) {
            float4 h4 = hv[m];
            a0 += wp[2 * m]     * (v2f){h4.x, h4.y};
            a1 += wp[2 * m + 1] * (v2f){h4.z, h4.w};
            float4 h5 = hv[m + 1];
            a2 += wp[2 * m + 2] * (v2f){h5.x, h5.y};
            a3 += wp[2 * m + 3] * (v2f){h5.z, h5.w};
        }
        v2f aa = (a0 + a1) + (a2 + a3);
        float s = aa.x + aa.y;

        // ---- pair reduce: ONE quad_perm DPP add (VALU pipe) ----
        s = pair_swap_add(s);

        // ---- finalize: even lane of each pair owns the row ----
        if (fin) {
            float hn = tanh_fast(xp_cur + s);
            hbuf[(t + 1) & 1][row] = hn;   // 32 lanes, stride-1 -> banks 0..31
            xp_cur = xp_next;
        }
        __syncthreads();   // single barrier per step (double-buffered h)
    }

    // ---- classifier head ----
    const float* hf = hbuf[len & 1];
    if (tid < 128) {
        int c = tid >> 6, l2 = tid & 63;
        float sacc = 0.f;
        #pragma unroll
        for (int q = 0; q < 4; ++q) {
            int idx = q * 64 + l2;
            sacc += Wcls[c * 256 + idx] * hf[idx];
        }
        #pragma unroll
        for (int off = 32; off > 0; off >>= 1)
            sacc += __shfl_down(sacc, off, 64);
        if (l2 == 0) out[b * 2 + c] = sacc + bcls[c];
    }
}

// ------------------------------- launcher ------------------------------------
extern "C" void kernel_launch(void* const* d_in, const int* in_sizes, int n_in,
                              void* d_out, int out_size, void* d_ws, size_t ws_size,
                              hipStream_t stream) {
    const int*   reviews = (const int*)d_in[0];
    const int*   lengths = (const int*)d_in[1];
    const float* emb     = (const float*)d_in[2];
    const float* W_ih    = (const float*)d_in[3];
    const float* W_hh    = (const float*)d_in[4];
    const float* W_cls   = (const float*)d_in[5];
    const float* b_cls   = (const float*)d_in[6];
    float* out = (float*)d_out;

    float* WT = (float*)d_ws;
    float* P  = WT + 256 * 256;

    k_transpose<<<256, 256, 0, stream>>>(W_ih, WT);
    k_project<<<(VOCAB + 31) / 32, 256, 0, stream>>>(emb, WT, P);
    k_rnn<<<BATCH, 512, 0, stream>>>(reviews, lengths, P, W_hh, W_cls, b_cls, out);
}